// Round 3
// baseline (509.749 us; speedup 1.0000x reference)
//
#include <hip/hip_runtime.h>
#include <cstddef>

#define BB 32
#define CC 320
#define HH 64
#define WW 64
#define CTX_HW 16
#define NPIX 256

typedef __attribute__((ext_vector_type(8))) short bf16x8;
typedef __attribute__((ext_vector_type(4))) float f32x4;

__device__ inline ushort f2bf(float x) {
  union { float f; unsigned u; } v; v.f = x;
  unsigned r = v.u + 0x7fff + ((v.u >> 16) & 1);  // RNE
  return (ushort)(r >> 16);
}

// ---------------------------------------------------------------------------
// Cast context (B,256,1024) fp32 -> pixel-major bf16 ctxP[B][257][1056]
// (ch 1024/1025 = indicator, 1026..1055 = 0, row 256 = zeros).
// Also zeroes row 256 of cx1P[B][257][320].
__global__ __launch_bounds__(256) void cast_ctx(
    const float* __restrict__ ctx, const float* __restrict__ ind,
    ushort* __restrict__ ctxP, ushort* __restrict__ cx1P) {
  int b = blockIdx.x, p = blockIdx.y, t = threadIdx.x;
  ushort* orow = ctxP + ((size_t)b * 257 + p) * 1056;
  if (p < 256) {
    const float* irow = ctx + ((size_t)b * 256 + p) * 1024;
    float4 v = ((const float4*)irow)[t];
    ushort4 o;
    o.x = f2bf(v.x); o.y = f2bf(v.y); o.z = f2bf(v.z); o.w = f2bf(v.w);
    ((ushort4*)orow)[t] = o;
    if (t < 32) {
      float val = (t == 0) ? ind[b * 2] : (t == 1) ? ind[b * 2 + 1] : 0.0f;
      orow[1024 + t] = f2bf(val);
    }
  } else {
    ushort4 z = make_ushort4(0, 0, 0, 0);
    for (int i = t; i < 264; i += 256) ((ushort4*)orow)[i] = z;
    if (t < 80) ((ushort4*)(cx1P + ((size_t)b * 257 + 256) * 320))[t] = z;
  }
}

// ---------------------------------------------------------------------------
// Weight transform: w[320][KIN][9] fp32 -> wT[9][320][KP] bf16 (ci zero-pad).
// Block per co: coalesced global read -> LDS, coalesced global write.
template <int KIN, int KP>
__global__ __launch_bounds__(256) void wt_tr(
    const float* __restrict__ w, ushort* __restrict__ wT) {
  __shared__ float wl[KIN * 9];
  int co = blockIdx.x, t = threadIdx.x;
  const float* wsrc = w + (size_t)co * KIN * 9;
  for (int i = t; i < KIN * 9; i += 256) wl[i] = wsrc[i];
  __syncthreads();
#pragma unroll
  for (int tap = 0; tap < 9; ++tap) {
    ushort* dst = wT + ((size_t)tap * 320 + co) * KP;
    for (int ci = t; ci < KP; ci += 256)
      dst[ci] = f2bf(ci < KIN ? wl[ci * 9 + tap] : 0.0f);
  }
}

// ---------------------------------------------------------------------------
// Per-batch gather maps: sy[b][y] = source row 0..15 or -1 if masked.
__global__ __launch_bounds__(64) void prep_maps(
    const float* __restrict__ bbox, int* __restrict__ sy, int* __restrict__ sx) {
  int b = blockIdx.x;
  int t = threadIdx.x;
  int x1 = (int)(bbox[b * 4 + 0] * (float)HH);
  int y1 = (int)(bbox[b * 4 + 1] * (float)HH);
  int x2 = max((int)(bbox[b * 4 + 2] * (float)HH), x1 + 1);
  int y2 = max((int)(bbox[b * 4 + 3] * (float)HH), y1 + 1);
  bool ok = (y2 <= HH) && (x2 <= WW) && (y1 >= 0) && (x1 >= 0);
  int vy = -1, vx = -1;
  if (ok && t >= y1 && t < y2) vy = min(15, max(0, ((t - y1) * CTX_HW) / (y2 - y1)));
  if (ok && t >= x1 && t < x2) vx = min(15, max(0, ((t - x1) * CTX_HW) / (x2 - x1)));
  sy[b * 64 + t] = vy;
  sx[b * 64 + t] = vx;
}

// ---------------------------------------------------------------------------
// K-split implicit-GEMM 3x3 SAME conv on 16x16 planes, bf16 MFMA.
// src: bf16 [BB][257][KP] (row 256 zeros); wT: bf16 [9][320][KP]
// part: fp32 [KS][BB][320][256] partial sums (no bias).
// Block = (b, 64-co tile, k-split); 512 thr = 8 waves; wave = 64 px x 32 co.
template <int KP, int NCH, int KS>
__global__ __launch_bounds__(512, 4) void conv_part(
    const ushort* __restrict__ src, const ushort* __restrict__ wT,
    float* __restrict__ part) {
  constexpr int PL = 40;  // LDS row stride (elems): 80 B, balanced banks
  __shared__ ushort plane[257 * PL];

  int b = blockIdx.x;
  int co0 = blockIdx.y * 64;
  int z = blockIdx.z;
  int c0 = z * NCH / KS, c1 = (z + 1) * NCH / KS;
  int tid = threadIdx.x;
  int wid = tid >> 6, lane = tid & 63;
  int m = lane & 15, quad = lane >> 4;
  int mg = wid >> 1, ng = wid & 1;
  int y0 = mg * 4;
  int coA = co0 + ng * 32 + m;  // nt=0 column; nt=1 is +16

  if (tid < PL) plane[256 * PL + tid] = 0;  // permanent zero row

  f32x4 acc[4][2];
#pragma unroll
  for (int i = 0; i < 4; ++i) {
    acc[i][0] = (f32x4)(0.0f);
    acc[i][1] = (f32x4)(0.0f);
  }

  const ushort* srcb = src + (size_t)b * 257 * KP;
  int row = tid >> 1, half = tid & 1;
  const ushort* gsrc = srcb + (size_t)row * KP + half * 16;
  ushort* lds_dst = plane + row * PL + half * 16;

  for (int cic = c0; cic < c1; ++cic) {
    __syncthreads();
    {  // stage 256 rows x 32 ci = 16 KB
      const float4* g = (const float4*)(gsrc + cic * 32);
      float4 v0 = g[0];
      float4 v1 = g[1];
      ((float4*)lds_dst)[0] = v0;
      ((float4*)lds_dst)[1] = v1;
    }
    __syncthreads();
    const ushort* wb0 = wT + (size_t)coA * KP + cic * 32 + quad * 8;
    const ushort* wb1 = wb0 + (size_t)16 * KP;
#pragma unroll
    for (int dx = 0; dx < 3; ++dx) {
      int sxp = m + dx - 1;
      bool vx = (unsigned)sxp < 16u;
      bf16x8 af[6];  // image rows y0-1 .. y0+4, shifted by dx
#pragma unroll
      for (int j = 0; j < 6; ++j) {
        int syr = y0 - 1 + j;
        bool v = vx && ((unsigned)syr < 16u);
        int ldsrow = v ? (syr * 16 + sxp) : 256;
        af[j] = *(const bf16x8*)(plane + ldsrow * PL + quad * 8);
      }
#pragma unroll
      for (int dy = 0; dy < 3; ++dy) {
        int tap = dy * 3 + dx;
        bf16x8 bf0 = *(const bf16x8*)(wb0 + (size_t)tap * 320 * KP);
        bf16x8 bf1 = *(const bf16x8*)(wb1 + (size_t)tap * 320 * KP);
#pragma unroll
        for (int mt = 0; mt < 4; ++mt) {
          acc[mt][0] = __builtin_amdgcn_mfma_f32_16x16x32_bf16(af[mt + dy], bf0,
                                                               acc[mt][0], 0, 0, 0);
          acc[mt][1] = __builtin_amdgcn_mfma_f32_16x16x32_bf16(af[mt + dy], bf1,
                                                               acc[mt][1], 0, 0, 0);
        }
      }
    }
  }

  float* pz = part + (size_t)z * BB * CC * NPIX + (size_t)b * CC * NPIX;
#pragma unroll
  for (int nt = 0; nt < 2; ++nt) {
    int co = coA + nt * 16;
#pragma unroll
    for (int mt = 0; mt < 4; ++mt) {
      *(f32x4*)(pz + (size_t)co * NPIX + (y0 + mt) * 16 + quad * 4) = acc[mt][nt];
    }
  }
}

// ---------------------------------------------------------------------------
// Combine conv1 partials: sum KS1=4 partials + bias, SiLU, cast bf16,
// transpose planar->pixel-major cx1P[BB][257][320].
// grid (b, 5 co-chunks of 64, 4 px-chunks of 64), 256 thr.
__global__ __launch_bounds__(256) void combine1(
    const float* __restrict__ part, const float* __restrict__ bias,
    ushort* __restrict__ cx1P) {
  __shared__ float tile[64][65];
  int b = blockIdx.x, co0 = blockIdx.y * 64, px0 = blockIdx.z * 64;
  int t = threadIdx.x;
  int tx = t & 63, ty = t >> 6;  // px, co-subgroup
  const float* pb = part + ((size_t)b * CC + co0) * NPIX + px0 + tx;
  constexpr size_t KSTR = (size_t)BB * CC * NPIX;
#pragma unroll
  for (int i = 0; i < 16; ++i) {
    int cs = ty * 16 + i;
    const float* p = pb + (size_t)cs * NPIX;
    float s = p[0] + p[KSTR] + p[2 * KSTR] + p[3 * KSTR] + bias[co0 + cs];
    s = s / (1.0f + __expf(-s));  // SiLU
    tile[cs][tx] = s;
  }
  __syncthreads();
  int px = t >> 2, g = t & 3;
  ushort* dst = cx1P + ((size_t)b * 257 + px0 + px) * 320 + co0 + g * 16;
  ushort4 o[4];
#pragma unroll
  for (int i = 0; i < 16; ++i)
    ((ushort*)o)[i] = f2bf(tile[g * 16 + i][px]);
#pragma unroll
  for (int i = 0; i < 4; ++i) ((ushort4*)dst)[i] = o[i];
}

// ---------------------------------------------------------------------------
// out = global_x + masked gather of (part2[0] + part2[1] + bias).
__global__ __launch_bounds__(256) void scatter_add(
    const float* __restrict__ gx, const float* __restrict__ p0,
    const float* __restrict__ p1, const float* __restrict__ b_out,
    const int* __restrict__ sy, const int* __restrict__ sx,
    float* __restrict__ out) {
  int blk = blockIdx.x;
  int part = blk & 3;
  int bc = blk >> 2;  // b*320 + c
  int b = bc / CC;
  float bo = b_out[bc % CC];
  int t = threadIdx.x;
  int e = part * 1024 + t * 4;
  int y = e >> 6, x0 = e & 63;
  size_t idx = (size_t)bc * 4096 + e;
  float4 g = *(const float4*)(gx + idx);
  int vy = sy[b * 64 + y];
  if (vy >= 0) {
    size_t base = (size_t)bc * NPIX + vy * 16;
    int v0 = sx[b * 64 + x0 + 0]; if (v0 >= 0) g.x += p0[base + v0] + p1[base + v0] + bo;
    int v1 = sx[b * 64 + x0 + 1]; if (v1 >= 0) g.y += p0[base + v1] + p1[base + v1] + bo;
    int v2 = sx[b * 64 + x0 + 2]; if (v2 >= 0) g.z += p0[base + v2] + p1[base + v2] + bo;
    int v3 = sx[b * 64 + x0 + 3]; if (v3 >= 0) g.w += p0[base + v3] + p1[base + v3] + bo;
  }
  *(float4*)(out + idx) = g;
}

// ---------------------------------------------------------------------------
extern "C" void kernel_launch(void* const* d_in, const int* in_sizes, int n_in,
                              void* d_out, int out_size, void* d_ws, size_t ws_size,
                              hipStream_t stream) {
  const float* gx    = (const float*)d_in[0];
  const float* ctx   = (const float*)d_in[1];
  const float* ind   = (const float*)d_in[2];
  const float* bbox  = (const float*)d_in[3];
  const float* w_in  = (const float*)d_in[4];
  const float* b_in  = (const float*)d_in[5];
  const float* w_out = (const float*)d_in[6];
  const float* b_out = (const float*)d_in[7];
  float* out = (float*)d_out;

  char* ws = (char*)d_ws;
  float* part1 = (float*)ws;              // [4][32][320][256] fp32 = 41.94 MB
  float* part2 = (float*)ws;              // [2][32][320][256] aliases part1
  ws += (size_t)4 * BB * CC * NPIX * 4;
  ushort* ctxP = (ushort*)ws; ws += (size_t)BB * 257 * 1056 * 2;  // 17.37 MB
  ushort* wT1  = (ushort*)ws; ws += (size_t)9 * 320 * 1056 * 2;   //  6.08 MB
  ushort* wT2  = (ushort*)ws; ws += (size_t)9 * 320 * 320 * 2;    //  1.84 MB
  ushort* cx1P = (ushort*)ws; ws += (size_t)BB * 257 * 320 * 2;   //  5.26 MB
  int* sy = (int*)ws;         ws += BB * 64 * 4;
  int* sx = (int*)ws;

  cast_ctx<<<dim3(BB, 257), 256, 0, stream>>>(ctx, ind, ctxP, cx1P);
  wt_tr<1026, 1056><<<320, 256, 0, stream>>>(w_in, wT1);
  wt_tr<320, 320><<<320, 256, 0, stream>>>(w_out, wT2);
  prep_maps<<<BB, 64, 0, stream>>>(bbox, sy, sx);
  conv_part<1056, 33, 4><<<dim3(BB, 5, 4), 512, 0, stream>>>(ctxP, wT1, part1);
  combine1<<<dim3(BB, 5, 4), 256, 0, stream>>>(part1, b_in, cx1P);
  conv_part<320, 10, 2><<<dim3(BB, 5, 2), 512, 0, stream>>>(cx1P, wT2, part2);
  scatter_add<<<BB * CC * 4, 256, 0, stream>>>(gx, part2, part2 + (size_t)BB * CC * NPIX,
                                               b_out, sy, sx, out);
}

// Round 4
// 469.520 us; speedup vs baseline: 1.0857x; 1.0857x over previous
//
#include <hip/hip_runtime.h>
#include <cstddef>

#define BB 32
#define CC 320
#define HH 64
#define WW 64
#define CTX_HW 16
#define NPIX 256

typedef __attribute__((ext_vector_type(8))) short bf16x8;
typedef __attribute__((ext_vector_type(4))) float f32x4;

__device__ inline ushort f2bf(float x) {
  union { float f; unsigned u; } v; v.f = x;
  unsigned r = v.u + 0x7fff + ((v.u >> 16) & 1);  // RNE
  return (ushort)(r >> 16);
}

// ---------------------------------------------------------------------------
// Cast context (B,256,1024) fp32 -> pixel-major bf16 ctxP[B][257][1056]
// (ch 1024/1025 = indicator, 1026..1055 = 0, row 256 = zeros).
// Also zeroes row 256 of cx1P[B][257][320].
__global__ __launch_bounds__(256) void cast_ctx(
    const float* __restrict__ ctx, const float* __restrict__ ind,
    ushort* __restrict__ ctxP, ushort* __restrict__ cx1P) {
  int b = blockIdx.x, p = blockIdx.y, t = threadIdx.x;
  ushort* orow = ctxP + ((size_t)b * 257 + p) * 1056;
  if (p < 256) {
    const float* irow = ctx + ((size_t)b * 256 + p) * 1024;
    float4 v = ((const float4*)irow)[t];
    ushort4 o;
    o.x = f2bf(v.x); o.y = f2bf(v.y); o.z = f2bf(v.z); o.w = f2bf(v.w);
    ((ushort4*)orow)[t] = o;
    if (t < 32) {
      float val = (t == 0) ? ind[b * 2] : (t == 1) ? ind[b * 2 + 1] : 0.0f;
      orow[1024 + t] = f2bf(val);
    }
  } else {
    ushort4 z = make_ushort4(0, 0, 0, 0);
    for (int i = t; i < 264; i += 256) ((ushort4*)orow)[i] = z;
    if (t < 80) ((ushort4*)(cx1P + ((size_t)b * 257 + 256) * 320))[t] = z;
  }
}

// ---------------------------------------------------------------------------
// Weight transform (both convs in one launch):
// w[320][KIN][9] fp32 -> wT[9][320][KP] bf16 (ci zero-pad).
__device__ inline void wt_body(const float* __restrict__ w, ushort* __restrict__ wT,
                               int co, int KIN, int KP, float* wl) {
  int t = threadIdx.x;
  const float* wsrc = w + (size_t)co * KIN * 9;
  for (int i = t; i < KIN * 9; i += 256) wl[i] = wsrc[i];
  __syncthreads();
#pragma unroll
  for (int tap = 0; tap < 9; ++tap) {
    ushort* dst = wT + ((size_t)tap * 320 + co) * KP;
    for (int ci = t; ci < KP; ci += 256)
      dst[ci] = f2bf(ci < KIN ? wl[ci * 9 + tap] : 0.0f);
  }
}

__global__ __launch_bounds__(256) void wt_both(
    const float* __restrict__ w_in, const float* __restrict__ w_out,
    ushort* __restrict__ wT1, ushort* __restrict__ wT2) {
  __shared__ float wl[1026 * 9];
  int blk = blockIdx.x;
  if (blk < 320) wt_body(w_in, wT1, blk, 1026, 1056, wl);
  else           wt_body(w_out, wT2, blk - 320, 320, 320, wl);
}

// ---------------------------------------------------------------------------
// K-split implicit-GEMM 3x3 SAME conv on 16x16 planes, bf16 MFMA.
// src: bf16 [BB][257][KP] (row 256 zeros); wT: bf16 [9][320][KP]
// part: fp32 [KS][BB][320][256] partial sums (no bias).
// Block = (b, 64-co tile, k-split); 512 thr = 8 waves; wave = 64 px x 32 co.
template <int KP, int NCH, int KS>
__global__ __launch_bounds__(512, 4) void conv_part(
    const ushort* __restrict__ src, const ushort* __restrict__ wT,
    float* __restrict__ part) {
  constexpr int PL = 32;  // LDS row stride: 64 B -> A-reads conflict-free
  __shared__ ushort plane[257 * PL];

  int b = blockIdx.x;
  int co0 = blockIdx.y * 64;
  int z = blockIdx.z;
  int c0 = z * NCH / KS, c1 = (z + 1) * NCH / KS;
  int tid = threadIdx.x;
  int wid = tid >> 6, lane = tid & 63;
  int m = lane & 15, quad = lane >> 4;
  int mg = wid >> 1, ng = wid & 1;
  int y0 = mg * 4;
  int coA = co0 + ng * 32 + m;  // nt=0 column; nt=1 is +16

  if (tid < PL) plane[256 * PL + tid] = 0;  // permanent zero row

  f32x4 acc[4][2];
#pragma unroll
  for (int i = 0; i < 4; ++i) {
    acc[i][0] = (f32x4)(0.0f);
    acc[i][1] = (f32x4)(0.0f);
  }

  const ushort* srcb = src + (size_t)b * 257 * KP;
  int row = tid >> 1, half = tid & 1;
  const ushort* gsrc = srcb + (size_t)row * KP + half * 16;
  ushort* lds_dst = plane + row * PL + half * 16;

  for (int cic = c0; cic < c1; ++cic) {
    __syncthreads();
    {  // stage 256 rows x 32 ci = 16 KB
      const float4* g = (const float4*)(gsrc + cic * 32);
      float4 v0 = g[0];
      float4 v1 = g[1];
      ((float4*)lds_dst)[0] = v0;
      ((float4*)lds_dst)[1] = v1;
    }
    __syncthreads();
    const ushort* wb0 = wT + (size_t)coA * KP + cic * 32 + quad * 8;
    const ushort* wb1 = wb0 + (size_t)16 * KP;
#pragma unroll
    for (int dx = 0; dx < 3; ++dx) {
      int sxp = m + dx - 1;
      bool vx = (unsigned)sxp < 16u;
      bf16x8 af[6];  // image rows y0-1 .. y0+4, shifted by dx
#pragma unroll
      for (int j = 0; j < 6; ++j) {
        int syr = y0 - 1 + j;
        bool v = vx && ((unsigned)syr < 16u);
        int ldsrow = v ? (syr * 16 + sxp) : 256;
        af[j] = *(const bf16x8*)(plane + ldsrow * PL + quad * 8);
      }
#pragma unroll
      for (int dy = 0; dy < 3; ++dy) {
        int tap = dy * 3 + dx;
        bf16x8 bf0 = *(const bf16x8*)(wb0 + (size_t)tap * 320 * KP);
        bf16x8 bf1 = *(const bf16x8*)(wb1 + (size_t)tap * 320 * KP);
#pragma unroll
        for (int mt = 0; mt < 4; ++mt) {
          acc[mt][0] = __builtin_amdgcn_mfma_f32_16x16x32_bf16(af[mt + dy], bf0,
                                                               acc[mt][0], 0, 0, 0);
          acc[mt][1] = __builtin_amdgcn_mfma_f32_16x16x32_bf16(af[mt + dy], bf1,
                                                               acc[mt][1], 0, 0, 0);
        }
      }
    }
  }

  float* pz = part + (size_t)z * BB * CC * NPIX + (size_t)b * CC * NPIX;
#pragma unroll
  for (int nt = 0; nt < 2; ++nt) {
    int co = coA + nt * 16;
#pragma unroll
    for (int mt = 0; mt < 4; ++mt) {
      *(f32x4*)(pz + (size_t)co * NPIX + (y0 + mt) * 16 + quad * 4) = acc[mt][nt];
    }
  }
}

// ---------------------------------------------------------------------------
// Combine conv1 partials: sum KS1=4 partials + bias, SiLU, cast bf16,
// transpose planar->pixel-major cx1P[BB][257][320].
__global__ __launch_bounds__(256) void combine1(
    const float* __restrict__ part, const float* __restrict__ bias,
    ushort* __restrict__ cx1P) {
  __shared__ float tile[64][65];
  int b = blockIdx.x, co0 = blockIdx.y * 64, px0 = blockIdx.z * 64;
  int t = threadIdx.x;
  int tx = t & 63, ty = t >> 6;
  const float* pb = part + ((size_t)b * CC + co0) * NPIX + px0 + tx;
  constexpr size_t KSTR = (size_t)BB * CC * NPIX;
#pragma unroll
  for (int i = 0; i < 16; ++i) {
    int cs = ty * 16 + i;
    const float* p = pb + (size_t)cs * NPIX;
    float s = p[0] + p[KSTR] + p[2 * KSTR] + p[3 * KSTR] + bias[co0 + cs];
    s = s / (1.0f + __expf(-s));  // SiLU
    tile[cs][tx] = s;
  }
  __syncthreads();
  int px = t >> 2, g = t & 3;
  ushort* dst = cx1P + ((size_t)b * 257 + px0 + px) * 320 + co0 + g * 16;
  ushort4 o[4];
#pragma unroll
  for (int i = 0; i < 16; ++i)
    ((ushort*)o)[i] = f2bf(tile[g * 16 + i][px]);
#pragma unroll
  for (int i = 0; i < 4; ++i) ((ushort4*)dst)[i] = o[i];
}

// ---------------------------------------------------------------------------
// out = global_x + masked gather of (p0 + p1 + bias), LDS-staged plane.
// One block per (b,c): stage 256-float local plane + maps, stream 64x64.
__global__ __launch_bounds__(256) void scatter_add(
    const float* __restrict__ gx, const float* __restrict__ p0,
    const float* __restrict__ p1, const float* __restrict__ b_out,
    const float* __restrict__ bbox, float* __restrict__ out) {
  __shared__ float lp[256];
  __shared__ int sxs[64], sys[64];
  int bc = blockIdx.x;  // b*320 + c
  int b = bc / CC, c = bc - b * CC;
  int t = threadIdx.x;

  lp[t] = p0[(size_t)bc * NPIX + t] + p1[(size_t)bc * NPIX + t] + b_out[c];
  if (t < 64) {
    int x1 = (int)(bbox[b * 4 + 0] * (float)HH);
    int y1 = (int)(bbox[b * 4 + 1] * (float)HH);
    int x2 = max((int)(bbox[b * 4 + 2] * (float)HH), x1 + 1);
    int y2 = max((int)(bbox[b * 4 + 3] * (float)HH), y1 + 1);
    bool ok = (y2 <= HH) && (x2 <= WW) && (y1 >= 0) && (x1 >= 0);
    int vy = -1, vx = -1;
    if (ok && t >= y1 && t < y2) vy = min(15, max(0, ((t - y1) * CTX_HW) / (y2 - y1)));
    if (ok && t >= x1 && t < x2) vx = min(15, max(0, ((t - x1) * CTX_HW) / (x2 - x1)));
    sys[t] = vy;
    sxs[t] = vx;
  }
  __syncthreads();

  const float4* gx4 = (const float4*)(gx + (size_t)bc * 4096);
  float4* out4 = (float4*)(out + (size_t)bc * 4096);
#pragma unroll
  for (int i = 0; i < 4; ++i) {
    int j = i * 256 + t;          // float4 index within plane
    float4 g = gx4[j];
    int y = j >> 4;
    int x0 = (j & 15) * 4;
    int vy = sys[y];
    if (vy >= 0) {
      const float* rowp = lp + vy * 16;
      int v0 = sxs[x0 + 0]; if (v0 >= 0) g.x += rowp[v0];
      int v1 = sxs[x0 + 1]; if (v1 >= 0) g.y += rowp[v1];
      int v2 = sxs[x0 + 2]; if (v2 >= 0) g.z += rowp[v2];
      int v3 = sxs[x0 + 3]; if (v3 >= 0) g.w += rowp[v3];
    }
    out4[j] = g;
  }
}

// ---------------------------------------------------------------------------
extern "C" void kernel_launch(void* const* d_in, const int* in_sizes, int n_in,
                              void* d_out, int out_size, void* d_ws, size_t ws_size,
                              hipStream_t stream) {
  const float* gx    = (const float*)d_in[0];
  const float* ctx   = (const float*)d_in[1];
  const float* ind   = (const float*)d_in[2];
  const float* bbox  = (const float*)d_in[3];
  const float* w_in  = (const float*)d_in[4];
  const float* b_in  = (const float*)d_in[5];
  const float* w_out = (const float*)d_in[6];
  const float* b_out = (const float*)d_in[7];
  float* out = (float*)d_out;

  char* ws = (char*)d_ws;
  float* part1 = (float*)ws;              // [4][32][320][256] fp32 = 41.94 MB
  float* part2 = (float*)ws;              // [2][32][320][256] aliases part1
  ws += (size_t)4 * BB * CC * NPIX * 4;
  ushort* ctxP = (ushort*)ws; ws += (size_t)BB * 257 * 1056 * 2;  // 17.37 MB
  ushort* wT1  = (ushort*)ws; ws += (size_t)9 * 320 * 1056 * 2;   //  6.08 MB
  ushort* wT2  = (ushort*)ws; ws += (size_t)9 * 320 * 320 * 2;    //  1.84 MB
  ushort* cx1P = (ushort*)ws; ws += (size_t)BB * 257 * 320 * 2;   //  5.26 MB

  cast_ctx<<<dim3(BB, 257), 256, 0, stream>>>(ctx, ind, ctxP, cx1P);
  wt_both<<<640, 256, 0, stream>>>(w_in, w_out, wT1, wT2);
  conv_part<1056, 33, 4><<<dim3(BB, 5, 4), 512, 0, stream>>>(ctxP, wT1, part1);
  combine1<<<dim3(BB, 5, 4), 256, 0, stream>>>(part1, b_in, cx1P);
  conv_part<320, 10, 2><<<dim3(BB, 5, 2), 512, 0, stream>>>(cx1P, wT2, part2);
  scatter_add<<<BB * CC, 256, 0, stream>>>(gx, part2, part2 + (size_t)BB * CC * NPIX,
                                           b_out, bbox, out);
}